// Round 13
// baseline (111.961 us; speedup 1.0000x reference)
//
#include <hip/hip_runtime.h>

// Problem: B=4, C=256, C4=64, N=4096, f32 in/out.
//   Q = Wqk@x; V = Wv@x + b; E = Q^T Q / 8; A = softmax_rows(E); out = V @ A
// Fused: out[c,m] = sum_n (V[c,n]/Z[n]) * exp(E[n,m]),  Z[n] = sum_m exp(E[n,m])
// exp via v_exp_f32: Qt scaled by sqrt(log2e/8). z: no shift (2^12 folded into
// u_kernel). av: SHIFT2=12 keeps P normal-f16. P stays IN REGISTERS (E-MFMA
// D-layout == PV B-frag of mfma_f32_16x16x16f16). 2-stage pipeline (R12).
// R13: OCCUPANCY A/B — av n-split 2 (grid 1024 = 4 blocks/CU, deterministic
// 2-contributor f32 atomicAdd onto memset-0 Out); z m-chunks of 64
// (grid 2048, Zp depth 4, ~80 VGPR). Inner loops unchanged from R12.

#define CC 256
#define C4C 64
#define NBATCH 4
#define NN 4096
#define QSCALE 0.42466089f   // sqrt(log2(e)/8)
#define SHIFT2 12.0f

typedef _Float16 f16;
typedef _Float16 half2v __attribute__((ext_vector_type(2)));
typedef _Float16 half4 __attribute__((ext_vector_type(4)));
typedef _Float16 half8 __attribute__((ext_vector_type(8)));
typedef __fp16 fp16x2 __attribute__((ext_vector_type(2)));
typedef float floatx4 __attribute__((ext_vector_type(4)));

static __device__ __forceinline__ half2v pkrtz(float a, float b) {
  fp16x2 r = __builtin_amdgcn_cvt_pkrtz(a, b);
  return __builtin_bit_cast(half2v, r);
}

// ---------------- QV: Q/V projections via MFMA ----------------
// grid (128, 4) block 256 (4 waves). Block tile: 128 oc x 32 n, K=C=256.
#define XT_PITCH 264
__global__ __launch_bounds__(256) void qv_kernel(
    const float* __restrict__ x, const float* __restrict__ Wqk,
    const float* __restrict__ Wv, const float* __restrict__ bv,
    f16* __restrict__ Qt, float* __restrict__ V)
{
  __shared__ __align__(16) f16 xt[32][XT_PITCH];
  const int b = blockIdx.y;
  const int n0 = blockIdx.x * 32;
  const int tid = threadIdx.x;

  {
    const int nq = tid & 7;
    const int cb = tid >> 3;
    const int c = cb * 8;
    const float* xp = x + (size_t)b * CC * NN + n0 + nq * 4;
    float4 r[8];
#pragma unroll
    for (int j = 0; j < 8; ++j)
      r[j] = *(const float4*)(xp + (size_t)(c + j) * NN);
#pragma unroll
    for (int s = 0; s < 4; ++s) {
      half8 h;
#pragma unroll
      for (int j = 0; j < 8; ++j) h[j] = (f16)(((const float*)&r[j])[s]);
      *(half8*)(&xt[nq * 4 + s][c]) = h;
    }
  }

  const int w = tid >> 6, l = tid & 63, lr = l & 15, lg = l >> 4;
  const float* Wsrc = (w < 2) ? Wqk : Wv;
  const int ocb = (w & 1) * 32;
  half8 af[2][8];
#pragma unroll
  for (int t = 0; t < 2; ++t) {
    const float* wp = Wsrc + (size_t)(ocb + t * 16 + lr) * CC + 8 * lg;
#pragma unroll
    for (int kk = 0; kk < 8; ++kk) {
      float4 wa = *(const float4*)(wp + kk * 32);
      float4 wb = *(const float4*)(wp + kk * 32 + 4);
      half8 h;
      h[0] = (f16)wa.x; h[1] = (f16)wa.y; h[2] = (f16)wa.z; h[3] = (f16)wa.w;
      h[4] = (f16)wb.x; h[5] = (f16)wb.y; h[6] = (f16)wb.z; h[7] = (f16)wb.w;
      af[t][kk] = h;
    }
  }

  __syncthreads();

  floatx4 acc[2][2] = {{{0.f,0.f,0.f,0.f},{0.f,0.f,0.f,0.f}},
                       {{0.f,0.f,0.f,0.f},{0.f,0.f,0.f,0.f}}};
#pragma unroll
  for (int nt = 0; nt < 2; ++nt) {
#pragma unroll
    for (int kk = 0; kk < 8; ++kk) {
      half8 bf = *(const half8*)(&xt[nt * 16 + lr][kk * 32 + 8 * lg]);
      acc[0][nt] = __builtin_amdgcn_mfma_f32_16x16x32_f16(af[0][kk], bf, acc[0][nt], 0, 0, 0);
      acc[1][nt] = __builtin_amdgcn_mfma_f32_16x16x32_f16(af[1][kk], bf, acc[1][nt], 0, 0, 0);
    }
  }

  if (w < 2) {
#pragma unroll
    for (int t = 0; t < 2; ++t)
#pragma unroll
      for (int nt = 0; nt < 2; ++nt) {
        int n = n0 + nt * 16 + lr;
        int oc = w * 32 + t * 16 + 4 * lg;
        union { f16 h[4]; unsigned long long u; } q4;
#pragma unroll
        for (int i = 0; i < 4; ++i) q4.h[i] = (f16)(acc[t][nt][i] * QSCALE);
        *(unsigned long long*)(Qt + ((size_t)(b * NN) + n) * 64 + oc) = q4.u;
      }
  } else {
#pragma unroll
    for (int t = 0; t < 2; ++t)
#pragma unroll
      for (int nt = 0; nt < 2; ++nt) {
        int n = n0 + nt * 16 + lr;
        int oc = (w - 2) * 32 + t * 16 + 4 * lg;
#pragma unroll
        for (int i = 0; i < 4; ++i)
          V[((size_t)(b * C4C) + oc + i) * NN + n] = acc[t][nt][i] + bv[oc + i];
      }
  }
}

// ---------------- Z pass: 2-stage pipeline, 64-m chunks, grid 2048 -----------
// Zp[mc][b][n0..n0+32) partial over a 1024-m quarter. Block 256 (4 waves);
// wave w: 256 m = 4 chunks of 64 (4 preloaded tiles each).
#define Z_PRELOAD4(MBEG)                                                   \
  { _Pragma("unroll")                                                      \
    for (int mt = 0; mt < 4; ++mt) {                                       \
      const f16* bp_ = Qb + ((size_t)((MBEG) + mt * 16 + lr)) * 64 + 8 * lg; \
      bb[mt][0] = *(const half8*)(bp_);                                    \
      bb[mt][1] = *(const half8*)(bp_ + 32);                               \
    } }

#define Z_E(MT, D0, D1)                                                    \
  { D0 = (floatx4){0.f,0.f,0.f,0.f}; D1 = (floatx4){0.f,0.f,0.f,0.f};      \
    D0 = __builtin_amdgcn_mfma_f32_16x16x32_f16(a[0][0], bb[MT][0], D0, 0, 0, 0); \
    D1 = __builtin_amdgcn_mfma_f32_16x16x32_f16(a[1][0], bb[MT][0], D1, 0, 0, 0); \
    D0 = __builtin_amdgcn_mfma_f32_16x16x32_f16(a[0][1], bb[MT][1], D0, 0, 0, 0); \
    D1 = __builtin_amdgcn_mfma_f32_16x16x32_f16(a[1][1], bb[MT][1], D1, 0, 0, 0); }

#define Z_SM(D0, D1)                                                       \
  { _Pragma("unroll")                                                      \
    for (int i = 0; i < 4; ++i) {                                          \
      rs[0][i] += __builtin_amdgcn_exp2f(D0[i]);                           \
      rs[1][i] += __builtin_amdgcn_exp2f(D1[i]); } }

__global__ __launch_bounds__(256) void z_kernel(
    const f16* __restrict__ Qt, float* __restrict__ Zp)
{
  __shared__ float zl[4][32];
  const int bx = blockIdx.x;
  const int xcd = bx & 7, slot = bx >> 3;       // slot 0..255
  const int b = xcd >> 1;                        // 2 XCDs per batch
  const int wu = ((xcd & 1) << 8) | slot;        // 0..511 per batch
  const int n0 = (wu >> 2) * 32;                 // nb 0..127
  const int mc = wu & 3;                         // m quarter
  const int tid = threadIdx.x;
  const int w = tid >> 6, l = tid & 63, lr = l & 15, lg = l >> 4;
  const f16* Qb = Qt + (size_t)b * NN * 64;

  half8 a[2][2];
#pragma unroll
  for (int t = 0; t < 2; ++t) {
    const f16* ap = Qb + ((size_t)(n0 + 16 * t + lr)) * 64 + 8 * lg;
    a[t][0] = *(const half8*)(ap);
    a[t][1] = *(const half8*)(ap + 32);
  }

  const int mstr = mc * 1024 + w * 256;
  half8 bb[4][2];
  floatx4 dA0, dA1, dB0, dB1;
  float rs[2][4] = {{0.f,0.f,0.f,0.f},{0.f,0.f,0.f,0.f}};

  // chunk 0: tiles 0..3 (tile 3 pending in dB)
  Z_PRELOAD4(mstr);
  Z_E(0, dA0, dA1);
  Z_E(1, dB0, dB1); Z_SM(dA0, dA1);
  Z_E(2, dA0, dA1); Z_SM(dB0, dB1);
  Z_E(3, dB0, dB1); Z_SM(dA0, dA1);
#pragma unroll 1
  for (int mch = 1; mch < 4; ++mch) {
    Z_PRELOAD4(mstr + mch * 64);
    Z_SM(dB0, dB1);          // pending tile from previous chunk
    Z_E(0, dA0, dA1);
    Z_E(1, dB0, dB1); Z_SM(dA0, dA1);
    Z_E(2, dA0, dA1); Z_SM(dB0, dB1);
    Z_E(3, dB0, dB1); Z_SM(dA0, dA1);
  }
  Z_SM(dB0, dB1);            // drain

#pragma unroll
  for (int t = 0; t < 2; ++t)
#pragma unroll
    for (int i = 0; i < 4; ++i) {
      float v = rs[t][i];
      v += __shfl_xor(v, 1); v += __shfl_xor(v, 2);
      v += __shfl_xor(v, 4); v += __shfl_xor(v, 8);
      rs[t][i] = v;
    }
  if (lr == 0) {
#pragma unroll
    for (int t = 0; t < 2; ++t)
#pragma unroll
      for (int i = 0; i < 4; ++i)
        zl[w][16 * t + 4 * lg + i] = rs[t][i];
  }
  __syncthreads();
  if (tid < 32) {   // fixed-order cross-wave sum: deterministic
    float s = zl[0][tid] + zl[1][tid] + zl[2][tid] + zl[3][tid];
    Zp[(size_t)mc * NBATCH * NN + b * NN + n0 + tid] = s;
  }
}

// ---------------- Z reduce: Z[i] = sum_{k<4} Zp[k][i] (fixed order) -----------
__global__ __launch_bounds__(256) void zr_kernel(
    const float* __restrict__ Zp, float* __restrict__ Z)
{
  int i = blockIdx.x * 256 + threadIdx.x;   // 4*4096 = 16384
  float s = 0.f;
#pragma unroll
  for (int k = 0; k < 4; ++k) s += Zp[(size_t)k * NBATCH * NN + i];
  Z[i] = s;
}

// ---------------- U: blocked U4[b][n/16][c][16] = V * 2^12 / Zraw (fp16) -------
__global__ __launch_bounds__(256) void u_kernel(
    const float* __restrict__ V, const float* __restrict__ Z,
    f16* __restrict__ U4)
{
  size_t t = (size_t)blockIdx.x * 256 + threadIdx.x;  // 128K threads
  size_t e = t * 8;
  int b = (int)(e >> 18);
  int c = (int)((e >> 12) & 63);
  int n = (int)(e & (NN - 1));
  const float* vp = V + (size_t)b * C4C * NN + (size_t)c * NN + n;
  float4 v0 = *(const float4*)(vp);
  float4 v1 = *(const float4*)(vp + 4);
  const float* zp = Z + b * NN + n;
  float4 z0 = *(const float4*)(zp);
  float4 z1 = *(const float4*)(zp + 4);
  half2v h0 = pkrtz(v0.x * 4096.0f / z0.x, v0.y * 4096.0f / z0.y);
  half2v h1 = pkrtz(v0.z * 4096.0f / z0.z, v0.w * 4096.0f / z0.w);
  half2v h2 = pkrtz(v1.x * 4096.0f / z1.x, v1.y * 4096.0f / z1.y);
  half2v h3 = pkrtz(v1.z * 4096.0f / z1.z, v1.w * 4096.0f / z1.w);
  half8 h = {h0[0], h0[1], h1[0], h1[1], h2[0], h2[1], h3[0], h3[1]};
  *(half8*)(U4 + (size_t)b * (C4C * NN) + (size_t)(n >> 4) * 1024 + c * 16 + (n & 15)) = h;
}

// ---------------- PV pass: 2-stage pipeline, n-split 2, grid 1024 ------------
// grid 1024 (XCD-swizzled) block 512 (8 waves) -> 4 blocks/CU (~32 waves/CU).
// Block: 32 m-cols x n-half (2048 n = 128 strips; wave w: 16 strips).
// Iter i: SMPV(i-1) -> LOAD(i+1) -> E(i). Depth-2 named buffers (R12).
// End: fixed-order 8-wave LDS reduce, then 2-contributor f32 atomicAdd
// (commutative -> bitwise deterministic on memset-0 Out).
#define LOADA(NS, A0, A1)                                                  \
  { const f16* ap_ = Qb + ((size_t)((NS) + lr)) * 64 + 8 * lg;             \
    A0 = *(const half8*)(ap_); A1 = *(const half8*)(ap_ + 32); }

#define LOADU(NB, UA)                                                      \
  { const f16* up_ = Ub + (size_t)(NB) * 1024 + 4 * lg;                    \
    _Pragma("unroll")                                                      \
    for (int cs = 0; cs < 4; ++cs)                                         \
      UA[cs] = *(const half4*)(up_ + (16 * cs + lr) * 16); }

#define E_STEP(A0, A1, DA, DB)                                             \
  { DA = (floatx4){0.f,0.f,0.f,0.f}; DB = (floatx4){0.f,0.f,0.f,0.f};      \
    DA = __builtin_amdgcn_mfma_f32_16x16x32_f16(A0, bq[0][0], DA, 0, 0, 0);\
    DB = __builtin_amdgcn_mfma_f32_16x16x32_f16(A0, bq[1][0], DB, 0, 0, 0);\
    DA = __builtin_amdgcn_mfma_f32_16x16x32_f16(A1, bq[0][1], DA, 0, 0, 0);\
    DB = __builtin_amdgcn_mfma_f32_16x16x32_f16(A1, bq[1][1], DB, 0, 0, 0); }

#define SMPV(DA, DB, UA)                                                   \
  { half2v p0a = pkrtz(__builtin_amdgcn_exp2f(DA[0] - SHIFT2),             \
                       __builtin_amdgcn_exp2f(DA[1] - SHIFT2));            \
    half2v p0b = pkrtz(__builtin_amdgcn_exp2f(DA[2] - SHIFT2),             \
                       __builtin_amdgcn_exp2f(DA[3] - SHIFT2));            \
    half2v p1a = pkrtz(__builtin_amdgcn_exp2f(DB[0] - SHIFT2),             \
                       __builtin_amdgcn_exp2f(DB[1] - SHIFT2));            \
    half2v p1b = pkrtz(__builtin_amdgcn_exp2f(DB[2] - SHIFT2),             \
                       __builtin_amdgcn_exp2f(DB[3] - SHIFT2));            \
    half4 bt0 = {p0a[0], p0a[1], p0b[0], p0b[1]};                          \
    half4 bt1 = {p1a[0], p1a[1], p1b[0], p1b[1]};                          \
    _Pragma("unroll")                                                      \
    for (int cs = 0; cs < 4; ++cs) {                                       \
      o[cs][0] = __builtin_amdgcn_mfma_f32_16x16x16f16(UA[cs], bt0, o[cs][0], 0, 0, 0); \
      o[cs][1] = __builtin_amdgcn_mfma_f32_16x16x16f16(UA[cs], bt1, o[cs][1], 0, 0, 0); } }

__global__ __launch_bounds__(512, 4) void av_kernel(
    const f16* __restrict__ Qt, const f16* __restrict__ U4,
    float* __restrict__ Out)
{
  __shared__ float red[8][2][16][17];  // ~17.4 KB

  const int bx = blockIdx.x;
  const int xcd = bx & 7, slot = bx >> 3;          // slot 0..127
  const int b = xcd >> 1;                          // 2 XCDs per batch
  const int wu = ((xcd & 1) << 7) | slot;          // 0..255 per batch
  const int m0 = (wu >> 1) * 32;                   // 128 m-tiles
  const int nh = wu & 1;                           // n-half
  const int sbase = nh * 128;                      // strip base (strip = 16 n)
  const int tid = threadIdx.x;
  const int w = tid >> 6;                          // 0..7
  const int l = tid & 63;
  const int lr = l & 15, lg = l >> 4;

  const f16* Qb = Qt + (size_t)b * NN * 64;
  const f16* Ub = U4 + (size_t)b * (C4C * NN);

  // hoisted E B-frags for the 32-m tile
  half8 bq[2][2];
#pragma unroll
  for (int t = 0; t < 2; ++t) {
    const f16* bp = Qb + ((size_t)(m0 + 16 * t + lr)) * 64 + 8 * lg;
    bq[t][0] = *(const half8*)(bp);
    bq[t][1] = *(const half8*)(bp + 32);
  }

  floatx4 o[4][2];
#pragma unroll
  for (int cs = 0; cs < 4; ++cs)
#pragma unroll
    for (int t = 0; t < 2; ++t) o[cs][t] = (floatx4){0.f, 0.f, 0.f, 0.f};

  // pipeline state (all depth-2, named). 16 steps: strips sbase+w+8i, i=0..15.
  half8 a0A, a0B, a1A, a1B;
  half4 u0[4], u1[4];
  floatx4 d0A, d0B, d1A, d1B;

  int s0 = sbase + w;
  LOADA(s0 * 16, a0A, a0B); LOADU(s0, u0);
  LOADA((s0 + 8) * 16, a1A, a1B); LOADU(s0 + 8, u1);
  E_STEP(a0A, a0B, d0A, d0B);
  int sl = s0 + 16;
#pragma unroll 1
  for (int k = 0; k < 7; ++k) {
    SMPV(d0A, d0B, u0);
    LOADA(sl * 16, a0A, a0B); LOADU(sl, u0); sl += 8;
    E_STEP(a1A, a1B, d1A, d1B);
    SMPV(d1A, d1B, u1);
    LOADA(sl * 16, a1A, a1B); LOADU(sl, u1); sl += 8;
    E_STEP(a0A, a0B, d0A, d0B);
  }
  SMPV(d0A, d0B, u0);
  E_STEP(a1A, a1B, d1A, d1B);
  SMPV(d1A, d1B, u1);

  // ---- 8-wave reduction, fixed order, then deterministic atomicAdd ----
#pragma unroll 1
  for (int cs = 0; cs < 4; ++cs) {
    __syncthreads();
#pragma unroll
    for (int t = 0; t < 2; ++t)
#pragma unroll
      for (int i = 0; i < 4; ++i)
        red[w][t][4 * lg + i][lr] = o[cs][t][i];
    __syncthreads();
    const int t = tid >> 8;              // 0..1
    const int r = (tid >> 4) & 15;       // 0..15
    const int col = tid & 15;            // 0..15
    float ssum = 0.f;
#pragma unroll
    for (int ww = 0; ww < 8; ++ww) ssum += red[ww][t][r][col];
    atomicAdd(&Out[((size_t)b * C4C + cs * 16 + r) * NN + m0 + t * 16 + col], ssum);
  }
}

// ---------------- launch ----------------
// ws layout (~8.45 MB, Zp aliased over U4 region — dead before U4 is written):
//   Qt  f16 [4][4096][64]      2 MiB    @ 0
//   V   f32 [4][64][4096]      4 MiB    @ 2 MiB
//   Z   f32 [4][4096]          64 KiB   @ 6 MiB
//   U4  f16 [4][256][64][16]   2 MiB    @ 6 MiB + 64 KiB
//   Zp  f32 [4][4][4096]       256 KiB  @ 6 MiB + 64 KiB (aliases U4)
extern "C" void kernel_launch(void* const* d_in, const int* in_sizes, int n_in,
                              void* d_out, int out_size, void* d_ws, size_t ws_size,
                              hipStream_t stream)
{
  const float* x   = (const float*)d_in[0];
  const float* Wqk = (const float*)d_in[1];
  const float* Wv  = (const float*)d_in[2];
  const float* bv  = (const float*)d_in[3];
  float* out = (float*)d_out;

  char* ws = (char*)d_ws;
  f16*   Qt = (f16*)(ws);
  float* V  = (float*)(ws + (2u << 20));
  float* Z  = (float*)(ws + (6u << 20));
  f16*   U4 = (f16*)(ws + (6u << 20) + (64u << 10));
  float* Zp = (float*)(ws + (6u << 20) + (64u << 10));  // alias: dead before U4

  hipMemsetAsync(out, 0, (size_t)out_size * sizeof(float), stream);

  qv_kernel<<<dim3(128, 4), 256, 0, stream>>>(x, Wqk, Wv, bv, Qt, V);
  z_kernel<<<dim3(2048), 256, 0, stream>>>(Qt, Zp);
  zr_kernel<<<dim3(64), 256, 0, stream>>>(Zp, Z);
  u_kernel<<<dim3(512), 256, 0, stream>>>(V, Z, U4);
  av_kernel<<<dim3(1024), 512, 0, stream>>>(Qt, U4, out);
}

// Round 14
// 65.590 us; speedup vs baseline: 1.7070x; 1.7070x over previous
//
#include <hip/hip_runtime.h>

// Problem: B=4, C=256, C4=64, N=4096, f32 in/out.
//   Q = Wqk@x; V = Wv@x + b; E = Q^T Q / 8; A = softmax_rows(E); out = V @ A
// Fused: out[c,m] = sum_n (V[c,n]/Z[n]) * exp(E[n,m]),  Z[n] = sum_m exp(E[n,m])
// exp via v_exp_f32: Qt scaled by sqrt(log2e/8). z: no shift (2^12 folded into
// u_kernel). av: SHIFT2=12 keeps P normal-f16. P stays IN REGISTERS (E-MFMA
// D-layout == PV B-frag of mfma_f32_16x16x16f16). 2-stage pipeline (R12).
// R14: FRAG-BLOCKED Qt layout. Qtb[b][tile][blk][lane][8f16] — per 16-n tile
// 2 KB contiguous; a tile-operand load is ONE contiguous 1-KB wave load
// (8 sequential lines) instead of a 16-scattered-line gather. This was the
// one pattern shared by all seven stuck variants (z ~39, av ~56).
// Since E = Qt Qt^T, A-frags and B-frags have IDENTICAL lane data -> one
// layout serves both sides.

#define CC 256
#define C4C 64
#define NBATCH 4
#define NN 4096
#define QSCALE 0.42466089f   // sqrt(log2(e)/8)
#define SHIFT2 12.0f

typedef _Float16 f16;
typedef _Float16 half2v __attribute__((ext_vector_type(2)));
typedef _Float16 half4 __attribute__((ext_vector_type(4)));
typedef _Float16 half8 __attribute__((ext_vector_type(8)));
typedef __fp16 fp16x2 __attribute__((ext_vector_type(2)));
typedef float floatx4 __attribute__((ext_vector_type(4)));

static __device__ __forceinline__ half2v pkrtz(float a, float b) {
  fp16x2 r = __builtin_amdgcn_cvt_pkrtz(a, b);
  return __builtin_bit_cast(half2v, r);
}

// Load one 16-n tile's MFMA frag pair: lane l gets {row=l&15, k=8*(l>>4)+j}
// A0: k in [0,32), A1: k in [32,64). 2 x 1KB contiguous per wave.
#define LOADQ(T, A0, A1)                                                   \
  { const f16* p_ = Qb + (size_t)(T) * 1024 + l * 8;                       \
    A0 = *(const half8*)(p_); A1 = *(const half8*)(p_ + 512); }

// ---------------- QV: Q/V projections via MFMA ----------------
// grid (128, 4) block 256 (4 waves). Block tile: 128 oc x 32 n, K=C=256.
// Q output -> frag-blocked Qtb; V output -> row-major (for u_kernel).
#define XT_PITCH 264
__global__ __launch_bounds__(256) void qv_kernel(
    const float* __restrict__ x, const float* __restrict__ Wqk,
    const float* __restrict__ Wv, const float* __restrict__ bv,
    f16* __restrict__ Qtb, float* __restrict__ V)
{
  __shared__ __align__(16) f16 xt[32][XT_PITCH];
  const int b = blockIdx.y;
  const int n0 = blockIdx.x * 32;
  const int tid = threadIdx.x;

  {
    const int nq = tid & 7;
    const int cb = tid >> 3;
    const int c = cb * 8;
    const float* xp = x + (size_t)b * CC * NN + n0 + nq * 4;
    float4 r[8];
#pragma unroll
    for (int j = 0; j < 8; ++j)
      r[j] = *(const float4*)(xp + (size_t)(c + j) * NN);
#pragma unroll
    for (int s = 0; s < 4; ++s) {
      half8 h;
#pragma unroll
      for (int j = 0; j < 8; ++j) h[j] = (f16)(((const float*)&r[j])[s]);
      *(half8*)(&xt[nq * 4 + s][c]) = h;
    }
  }

  const int w = tid >> 6, l = tid & 63, lr = l & 15, lg = l >> 4;
  const float* Wsrc = (w < 2) ? Wqk : Wv;
  const int ocb = (w & 1) * 32;
  half8 af[2][8];
#pragma unroll
  for (int t = 0; t < 2; ++t) {
    const float* wp = Wsrc + (size_t)(ocb + t * 16 + lr) * CC + 8 * lg;
#pragma unroll
    for (int kk = 0; kk < 8; ++kk) {
      float4 wa = *(const float4*)(wp + kk * 32);
      float4 wb = *(const float4*)(wp + kk * 32 + 4);
      half8 h;
      h[0] = (f16)wa.x; h[1] = (f16)wa.y; h[2] = (f16)wa.z; h[3] = (f16)wa.w;
      h[4] = (f16)wb.x; h[5] = (f16)wb.y; h[6] = (f16)wb.z; h[7] = (f16)wb.w;
      af[t][kk] = h;
    }
  }

  __syncthreads();

  floatx4 acc[2][2] = {{{0.f,0.f,0.f,0.f},{0.f,0.f,0.f,0.f}},
                       {{0.f,0.f,0.f,0.f},{0.f,0.f,0.f,0.f}}};
#pragma unroll
  for (int nt = 0; nt < 2; ++nt) {
#pragma unroll
    for (int kk = 0; kk < 8; ++kk) {
      half8 bf = *(const half8*)(&xt[nt * 16 + lr][kk * 32 + 8 * lg]);
      acc[0][nt] = __builtin_amdgcn_mfma_f32_16x16x32_f16(af[0][kk], bf, acc[0][nt], 0, 0, 0);
      acc[1][nt] = __builtin_amdgcn_mfma_f32_16x16x32_f16(af[1][kk], bf, acc[1][nt], 0, 0, 0);
    }
  }

  if (w < 2) {
    // Q: blocked write. D col n = n0+nt*16+lr (tile T, row r=lr), rows oc.
    // oc = w*32 + t*16 + 4*lg + i -> blk=w, kg=2t+(lg>>1), j=4*(lg&1)+i.
    // dest f16 idx = T*1024 + w*512 + (kg*16 + lr)*8 + (lg&1)*4  (8-B store)
#pragma unroll
    for (int t = 0; t < 2; ++t)
#pragma unroll
      for (int nt = 0; nt < 2; ++nt) {
        int T = (n0 >> 4) + nt;
        int kg = 2 * t + (lg >> 1);
        union { f16 h[4]; unsigned long long u; } q4;
#pragma unroll
        for (int i = 0; i < 4; ++i) q4.h[i] = (f16)(acc[t][nt][i] * QSCALE);
        *(unsigned long long*)(Qtb + (size_t)(b * 256 + T) * 1024 + w * 512
                               + (kg * 16 + lr) * 8 + (lg & 1) * 4) = q4.u;
      }
  } else {
#pragma unroll
    for (int t = 0; t < 2; ++t)
#pragma unroll
      for (int nt = 0; nt < 2; ++nt) {
        int n = n0 + nt * 16 + lr;
        int oc = (w - 2) * 32 + t * 16 + 4 * lg;
#pragma unroll
        for (int i = 0; i < 4; ++i)
          V[((size_t)(b * C4C) + oc + i) * NN + n] = acc[t][nt][i] + bv[oc + i];
      }
  }
}

// ---------------- Z pass: 2-stage pipeline, blocked Qt loads -----------------
// Zp[mh][b][n0..n0+32) partial over a 2048-m half. grid 1024 (XCD-swizzled),
// block 256 (4 waves). Wave w: 512 m = 4 chunks of 128 (8 preloaded tiles).
#define Z_PRELOAD(TBEG)                                                    \
  { _Pragma("unroll")                                                      \
    for (int mt = 0; mt < 8; ++mt) {                                       \
      const f16* p_ = Qb + (size_t)((TBEG) + mt) * 1024 + l * 8;           \
      bb[mt][0] = *(const half8*)(p_);                                     \
      bb[mt][1] = *(const half8*)(p_ + 512);                               \
    } }

#define Z_E(MT, D0, D1)                                                    \
  { D0 = (floatx4){0.f,0.f,0.f,0.f}; D1 = (floatx4){0.f,0.f,0.f,0.f};      \
    D0 = __builtin_amdgcn_mfma_f32_16x16x32_f16(a[0][0], bb[MT][0], D0, 0, 0, 0); \
    D1 = __builtin_amdgcn_mfma_f32_16x16x32_f16(a[1][0], bb[MT][0], D1, 0, 0, 0); \
    D0 = __builtin_amdgcn_mfma_f32_16x16x32_f16(a[0][1], bb[MT][1], D0, 0, 0, 0); \
    D1 = __builtin_amdgcn_mfma_f32_16x16x32_f16(a[1][1], bb[MT][1], D1, 0, 0, 0); }

#define Z_SM(D0, D1)                                                       \
  { _Pragma("unroll")                                                      \
    for (int i = 0; i < 4; ++i) {                                          \
      rs[0][i] += __builtin_amdgcn_exp2f(D0[i]);                           \
      rs[1][i] += __builtin_amdgcn_exp2f(D1[i]); } }

#define Z_TILES17                                                          \
  Z_E(1, dB0, dB1); Z_SM(dA0, dA1);                                        \
  Z_E(2, dA0, dA1); Z_SM(dB0, dB1);                                        \
  Z_E(3, dB0, dB1); Z_SM(dA0, dA1);                                        \
  Z_E(4, dA0, dA1); Z_SM(dB0, dB1);                                        \
  Z_E(5, dB0, dB1); Z_SM(dA0, dA1);                                        \
  Z_E(6, dA0, dA1); Z_SM(dB0, dB1);                                        \
  Z_E(7, dB0, dB1); Z_SM(dA0, dA1);

__global__ __launch_bounds__(256) void z_kernel(
    const f16* __restrict__ Qtb, float* __restrict__ Zp)
{
  __shared__ float zl[4][32];
  const int bx = blockIdx.x;
  const int xcd = bx & 7, slot = bx >> 3;       // slot 0..127
  const int b = xcd >> 1;                        // 2 XCDs per batch
  const int wu = ((xcd & 1) << 7) | slot;        // 0..255 per batch
  const int n0 = (wu >> 1) * 32;                 // nb 0..127
  const int mh = wu & 1;                         // m half
  const int tid = threadIdx.x;
  const int w = tid >> 6, l = tid & 63, lr = l & 15, lg = l >> 4;
  const f16* Qb = Qtb + (size_t)b * 256 * 1024;

  half8 a[2][2];
  LOADQ((n0 >> 4), a[0][0], a[0][1]);
  LOADQ((n0 >> 4) + 1, a[1][0], a[1][1]);

  const int tstr = mh * 128 + w * 32;            // tile base (512 m = 32 tiles)
  half8 bb[8][2];
  floatx4 dA0, dA1, dB0, dB1;
  float rs[2][4] = {{0.f,0.f,0.f,0.f},{0.f,0.f,0.f,0.f}};

  Z_PRELOAD(tstr);
  Z_E(0, dA0, dA1);
  Z_TILES17;
#pragma unroll 1
  for (int mch = 1; mch < 4; ++mch) {
    Z_PRELOAD(tstr + mch * 8);
    Z_SM(dB0, dB1);
    Z_E(0, dA0, dA1);
    Z_TILES17;
  }
  Z_SM(dB0, dB1);

#pragma unroll
  for (int t = 0; t < 2; ++t)
#pragma unroll
    for (int i = 0; i < 4; ++i) {
      float v = rs[t][i];
      v += __shfl_xor(v, 1); v += __shfl_xor(v, 2);
      v += __shfl_xor(v, 4); v += __shfl_xor(v, 8);
      rs[t][i] = v;
    }
  if (lr == 0) {
#pragma unroll
    for (int t = 0; t < 2; ++t)
#pragma unroll
      for (int i = 0; i < 4; ++i)
        zl[w][16 * t + 4 * lg + i] = rs[t][i];
  }
  __syncthreads();
  if (tid < 32) {   // fixed-order cross-wave sum: deterministic
    float s = zl[0][tid] + zl[1][tid] + zl[2][tid] + zl[3][tid];
    Zp[(size_t)mh * NBATCH * NN + b * NN + n0 + tid] = s;
  }
}

// ---------------- Z reduce: Z[i] = Zp[0][i] + Zp[1][i] (fixed order) ----------
__global__ __launch_bounds__(256) void zr_kernel(
    const float* __restrict__ Zp, float* __restrict__ Z)
{
  int i = blockIdx.x * 256 + threadIdx.x;   // 4*4096 = 16384
  Z[i] = Zp[i] + Zp[(size_t)NBATCH * NN + i];
}

// ---------------- U: blocked U4[b][n/16][c][16] = V * 2^12 / Zraw (fp16) -------
__global__ __launch_bounds__(256) void u_kernel(
    const float* __restrict__ V, const float* __restrict__ Z,
    f16* __restrict__ U4)
{
  size_t t = (size_t)blockIdx.x * 256 + threadIdx.x;  // 128K threads
  size_t e = t * 8;
  int b = (int)(e >> 18);
  int c = (int)((e >> 12) & 63);
  int n = (int)(e & (NN - 1));
  const float* vp = V + (size_t)b * C4C * NN + (size_t)c * NN + n;
  float4 v0 = *(const float4*)(vp);
  float4 v1 = *(const float4*)(vp + 4);
  const float* zp = Z + b * NN + n;
  float4 z0 = *(const float4*)(zp);
  float4 z1 = *(const float4*)(zp + 4);
  half2v h0 = pkrtz(v0.x * 4096.0f / z0.x, v0.y * 4096.0f / z0.y);
  half2v h1 = pkrtz(v0.z * 4096.0f / z0.z, v0.w * 4096.0f / z0.w);
  half2v h2 = pkrtz(v1.x * 4096.0f / z1.x, v1.y * 4096.0f / z1.y);
  half2v h3 = pkrtz(v1.z * 4096.0f / z1.z, v1.w * 4096.0f / z1.w);
  half8 h = {h0[0], h0[1], h1[0], h1[1], h2[0], h2[1], h3[0], h3[1]};
  *(half8*)(U4 + (size_t)b * (C4C * NN) + (size_t)(n >> 4) * 1024 + c * 16 + (n & 15)) = h;
}

// ---------------- PV pass: 2-stage pipeline, blocked Qt loads ----------------
// grid 512 (XCD-swizzled) block 512 (8 waves, (512,4)). Block: 32 m, all n.
// Wave w: strips (tiles) w+8i, i=0..31. Iter: SMPV(i-1) -> LOAD(i+1) -> E(i).
// End: fixed-order 8-wave LDS reduction (deterministic), direct stores.
#define LOADU(NB, UA)                                                      \
  { const f16* up_ = Ub + (size_t)(NB) * 1024 + 4 * lg;                    \
    _Pragma("unroll")                                                      \
    for (int cs = 0; cs < 4; ++cs)                                         \
      UA[cs] = *(const half4*)(up_ + (16 * cs + lr) * 16); }

#define E_STEP(A0, A1, DA, DB)                                             \
  { DA = (floatx4){0.f,0.f,0.f,0.f}; DB = (floatx4){0.f,0.f,0.f,0.f};      \
    DA = __builtin_amdgcn_mfma_f32_16x16x32_f16(A0, bq[0][0], DA, 0, 0, 0);\
    DB = __builtin_amdgcn_mfma_f32_16x16x32_f16(A0, bq[1][0], DB, 0, 0, 0);\
    DA = __builtin_amdgcn_mfma_f32_16x16x32_f16(A1, bq[0][1], DA, 0, 0, 0);\
    DB = __builtin_amdgcn_mfma_f32_16x16x32_f16(A1, bq[1][1], DB, 0, 0, 0); }

#define SMPV(DA, DB, UA)                                                   \
  { half2v p0a = pkrtz(__builtin_amdgcn_exp2f(DA[0] - SHIFT2),             \
                       __builtin_amdgcn_exp2f(DA[1] - SHIFT2));            \
    half2v p0b = pkrtz(__builtin_amdgcn_exp2f(DA[2] - SHIFT2),             \
                       __builtin_amdgcn_exp2f(DA[3] - SHIFT2));            \
    half2v p1a = pkrtz(__builtin_amdgcn_exp2f(DB[0] - SHIFT2),             \
                       __builtin_amdgcn_exp2f(DB[1] - SHIFT2));            \
    half2v p1b = pkrtz(__builtin_amdgcn_exp2f(DB[2] - SHIFT2),             \
                       __builtin_amdgcn_exp2f(DB[3] - SHIFT2));            \
    half4 bt0 = {p0a[0], p0a[1], p0b[0], p0b[1]};                          \
    half4 bt1 = {p1a[0], p1a[1], p1b[0], p1b[1]};                          \
    _Pragma("unroll")                                                      \
    for (int cs = 0; cs < 4; ++cs) {                                       \
      o[cs][0] = __builtin_amdgcn_mfma_f32_16x16x16f16(UA[cs], bt0, o[cs][0], 0, 0, 0); \
      o[cs][1] = __builtin_amdgcn_mfma_f32_16x16x16f16(UA[cs], bt1, o[cs][1], 0, 0, 0); } }

__global__ __launch_bounds__(512, 4) void av_kernel(
    const f16* __restrict__ Qtb, const f16* __restrict__ U4,
    float* __restrict__ Out)
{
  __shared__ float red[8][2][16][17];  // ~17.4 KB

  const int bx = blockIdx.x;
  const int xcd = bx & 7, slot = bx >> 3;          // slot 0..63
  const int b = xcd >> 1;                          // 2 XCDs per batch
  const int m0 = (((xcd & 1) << 6) | slot) * 32;   // 128 m-tiles per batch
  const int tid = threadIdx.x;
  const int w = tid >> 6;                          // 0..7
  const int l = tid & 63;
  const int lr = l & 15, lg = l >> 4;

  const f16* Qb = Qtb + (size_t)b * 256 * 1024;
  const f16* Ub = U4 + (size_t)b * (C4C * NN);

  // hoisted E B-frags for the 32-m tile (tiles m0/16, m0/16+1)
  half8 bq[2][2];
  LOADQ((m0 >> 4), bq[0][0], bq[0][1]);
  LOADQ((m0 >> 4) + 1, bq[1][0], bq[1][1]);

  floatx4 o[4][2];
#pragma unroll
  for (int cs = 0; cs < 4; ++cs)
#pragma unroll
    for (int t = 0; t < 2; ++t) o[cs][t] = (floatx4){0.f, 0.f, 0.f, 0.f};

  // pipeline state (all depth-2, named)
  half8 a0A, a0B, a1A, a1B;
  half4 u0[4], u1[4];
  floatx4 d0A, d0B, d1A, d1B;

  LOADQ(w, a0A, a0B); LOADU(w, u0);
  LOADQ(w + 8, a1A, a1B); LOADU(w + 8, u1);
  E_STEP(a0A, a0B, d0A, d0B);
  int sl = w + 16;
#pragma unroll 1
  for (int k = 0; k < 15; ++k) {
    SMPV(d0A, d0B, u0);
    LOADQ(sl, a0A, a0B); LOADU(sl, u0); sl += 8;
    E_STEP(a1A, a1B, d1A, d1B);
    SMPV(d1A, d1B, u1);
    LOADQ(sl, a1A, a1B); LOADU(sl, u1); sl += 8;
    E_STEP(a0A, a0B, d0A, d0B);
  }
  SMPV(d0A, d0B, u0);
  E_STEP(a1A, a1B, d1A, d1B);
  SMPV(d1A, d1B, u1);

  // ---- 8-wave reduction, fixed order: deterministic, no atomics ----
#pragma unroll 1
  for (int cs = 0; cs < 4; ++cs) {
    __syncthreads();
#pragma unroll
    for (int t = 0; t < 2; ++t)
#pragma unroll
      for (int i = 0; i < 4; ++i)
        red[w][t][4 * lg + i][lr] = o[cs][t][i];
    __syncthreads();
    const int t = tid >> 8;              // 0..1
    const int r = (tid >> 4) & 15;       // 0..15
    const int col = tid & 15;            // 0..15
    float ssum = 0.f;
#pragma unroll
    for (int ww = 0; ww < 8; ++ww) ssum += red[ww][t][r][col];
    Out[((size_t)b * C4C + cs * 16 + r) * NN + m0 + t * 16 + col] = ssum;
  }
}

// ---------------- launch ----------------
// ws layout (~8.45 MB, Zp aliased over U4 region — dead before U4 is written):
//   Qtb f16 [4][256][2][64][8] 2 MiB    @ 0   (frag-blocked)
//   V   f32 [4][64][4096]      4 MiB    @ 2 MiB
//   Z   f32 [4][4096]          64 KiB   @ 6 MiB
//   U4  f16 [4][256][64][16]   2 MiB    @ 6 MiB + 64 KiB
//   Zp  f32 [2][4][4096]       128 KiB  @ 6 MiB + 64 KiB (aliases U4)
extern "C" void kernel_launch(void* const* d_in, const int* in_sizes, int n_in,
                              void* d_out, int out_size, void* d_ws, size_t ws_size,
                              hipStream_t stream)
{
  const float* x   = (const float*)d_in[0];
  const float* Wqk = (const float*)d_in[1];
  const float* Wv  = (const float*)d_in[2];
  const float* bv  = (const float*)d_in[3];
  float* out = (float*)d_out;

  char* ws = (char*)d_ws;
  f16*   Qtb = (f16*)(ws);
  float* V   = (float*)(ws + (2u << 20));
  float* Z   = (float*)(ws + (6u << 20));
  f16*   U4  = (f16*)(ws + (6u << 20) + (64u << 10));
  float* Zp  = (float*)(ws + (6u << 20) + (64u << 10));  // alias: dead before U4

  qv_kernel<<<dim3(128, 4), 256, 0, stream>>>(x, Wqk, Wv, bv, Qtb, V);
  z_kernel<<<dim3(1024), 256, 0, stream>>>(Qtb, Zp);
  zr_kernel<<<dim3(64), 256, 0, stream>>>(Zp, Z);
  u_kernel<<<dim3(512), 256, 0, stream>>>(V, Z, U4);
  av_kernel<<<dim3(512), 512, 0, stream>>>(Qtb, U4, out);
}